// Round 7
// baseline (291.052 us; speedup 1.0000x reference)
//
#include <hip/hip_runtime.h>

// ClusteringLayer v6 on gfx950 — v5 + 2 waves/SIMD (512-thread persistent blocks).
// q = normalize(1/(1+dist2)), dist2 = xsq + csq - 2 x.c (exact fp32 xsq/csq;
// cross via bf16 MFMA, one-sided split x = x_hi + x_lo => 2 MFMA passes).
//
// v5 confirmed drain-serialization theory (133->~90 µs): persistent blocks +
// vmem-free K-loop (B in LDS) + prefetch-before-stores keeps the NT write
// queue continuously full. Harness fill proves writes sustain 6.5 TB/s, so
// the remaining gap (90 vs ~49 µs traffic floor) is latency: v5 ran 1
// wave/SIMD (131 KB LDS -> 1 block/CU x 4 waves). v6: 512-thread blocks,
// 8 independent 16-row wave-strips sharing the one LDS B copy -> 2
// waves/SIMD, same structure otherwise. No barriers in the loop.

#define DIM 128
#define NK  256

typedef __attribute__((ext_vector_type(8))) short short8;
typedef __attribute__((ext_vector_type(4))) float floatx4;

__device__ __forceinline__ unsigned short bf16_rne(float f) {
    unsigned int u = __float_as_uint(f);
    return (unsigned short)((u + 0x7fffu + ((u >> 16) & 1u)) >> 16);
}
__device__ __forceinline__ float bf16_f(unsigned short h) {
    return __uint_as_float(((unsigned int)h) << 16);
}

// ---------------------------------------------------------------------------
// prep: blocks 0-7 pack C into B-fragment order: 16B frag index
//   gid = ct*256 + ks*64 + lane  holds  c_bf16[col = ct*16 + (lane&15)]
//                                        [k = ks*32 + (lane>>4)*8 + j], j=0..7
// block 8: exact fp32 csq[col] = sum_k c[col][k]^2.
// ---------------------------------------------------------------------------
__global__ void prep_clusters(const float* __restrict__ c,
                              unsigned short* __restrict__ wb,
                              float* __restrict__ wcsq)
{
    if (blockIdx.x < 8) {
        const int gid  = blockIdx.x * 512 + threadIdx.x;  // 0..4095
        const int lane = gid & 63;
        const int ks   = (gid >> 6) & 3;
        const int ct   = gid >> 8;
        const int lm   = lane & 15;
        const int q4   = lane >> 4;
        const int col  = ct * 16 + lm;
        const float4* cg = (const float4*)(c + col * DIM + ks * 32 + q4 * 8);
        float4 v0 = cg[0], v1 = cg[1];
        const float* f0 = (const float*)&v0;
        const float* f1 = (const float*)&v1;
        union { unsigned short u[8]; short8 v; } B;
        #pragma unroll
        for (int i = 0; i < 4; ++i) B.u[i] = bf16_rne(f0[i]);
        #pragma unroll
        for (int i = 0; i < 4; ++i) B.u[4 + i] = bf16_rne(f1[i]);
        ((short8*)wb)[gid] = B.v;
    } else {
        const int t = threadIdx.x;
        const int col = t >> 1, half = t & 1;
        const float4* cg = (const float4*)(c + col * DIM + half * 64);
        float s = 0.f;
        #pragma unroll
        for (int i = 0; i < 16; ++i) {
            float4 v = cg[i];
            s = fmaf(v.x, v.x, s); s = fmaf(v.y, v.y, s);
            s = fmaf(v.z, v.z, s); s = fmaf(v.w, v.w, s);
        }
        s += __shfl_xor(s, 1);   // partner thread, same col
        if (!half) wcsq[col] = s;
    }
}

// prefetch the 16-row strip s: lane covers row s*16 + lm, k = ks*32 + q4*8 + j
__device__ __forceinline__ void prefetch_x(const float* __restrict__ x,
                                           int s, int lm, int q4,
                                           float4 pf[8]) {
    const float* xr = x + ((size_t)s * 16 + lm) * DIM;
    #pragma unroll
    for (int ks = 0; ks < 4; ++ks) {
        const float4* xg = (const float4*)(xr + ks * 32 + q4 * 8);
        pf[2 * ks]     = xg[0];
        pf[2 * ks + 1] = xg[1];
    }
}

// ---------------------------------------------------------------------------
// main: 512 threads = 8 independent waves; persistent over 16-row strips.
// iteration t: wave w -> strip t*8 + w (rows [strip*16, +16)).
// ---------------------------------------------------------------------------
__global__ __launch_bounds__(512, 2) void cluster_q_v6(
    const float* __restrict__ x,
    const unsigned short* __restrict__ wb,
    const float* __restrict__ wcsq,
    float* __restrict__ out,
    const int S,     // total strips = N/16
    const int NTB)   // ceil(S/8)
{
    __shared__ __align__(16) unsigned short bs[32768];   // 64 KiB: B fragments
    __shared__ float csq_s[NK];
    __shared__ __align__(16) float lt[8][2][4][264];     // per-wave transpose

    const int tid  = threadIdx.x;
    const int wave = tid >> 6;
    const int lane = tid & 63;
    const int lm   = lane & 15;
    const int q4   = lane >> 4;

    // ---- stage full B (64 KiB) + csq into LDS, once per block ----
    if (tid < NK) csq_s[tid] = wcsq[tid];
    for (int i = tid; i < 4096; i += 512) {
        float4 v = ((const float4*)wb)[i];
        *(float4*)&bs[i * 8] = v;
    }
    __syncthreads();   // the only barrier

    float4 pf[8];
    int t = blockIdx.x;
    int s = t * 8 + wave;
    if (t < NTB && s < S) prefetch_x(x, s, lm, q4, pf);

    while (t < NTB) {
        const bool active = (s < S);         // wave-uniform
        short8 ah[4], al[4];
        float xq = 0.f;
        floatx4 acc[16];

        if (active) {
            // ---- convert prefetched x -> A fragments (hi/lo) + row norm ----
            #pragma unroll
            for (int ks = 0; ks < 4; ++ks) {
                const float* f0 = (const float*)&pf[2 * ks];
                const float* f1 = (const float*)&pf[2 * ks + 1];
                union { unsigned short u[8]; short8 v; } H, L;
                #pragma unroll
                for (int i = 0; i < 4; ++i) {
                    float f = f0[i];
                    xq = fmaf(f, f, xq);
                    unsigned short h = bf16_rne(f);
                    H.u[i] = h;
                    L.u[i] = bf16_rne(f - bf16_f(h));
                }
                #pragma unroll
                for (int i = 0; i < 4; ++i) {
                    float f = f1[i];
                    xq = fmaf(f, f, xq);
                    unsigned short h = bf16_rne(f);
                    H.u[4 + i] = h;
                    L.u[4 + i] = bf16_rne(f - bf16_f(h));
                }
                ah[ks] = H.v;
                al[ks] = L.v;
            }
            xq += __shfl_xor(xq, 16);
            xq += __shfl_xor(xq, 32);

            // ---- K loop: B from LDS (zero vmem ops) ----
            #pragma unroll
            for (int ct = 0; ct < 16; ++ct) {
                floatx4 a = (floatx4){0.f, 0.f, 0.f, 0.f};
                #pragma unroll
                for (int ks = 0; ks < 4; ++ks) {
                    short8 b = *(const short8*)&bs[(ct * 256 + ks * 64 + lane) * 8];
                    a = __builtin_amdgcn_mfma_f32_16x16x32_bf16(ah[ks], b, a, 0, 0, 0);
                    a = __builtin_amdgcn_mfma_f32_16x16x32_bf16(al[ks], b, a, 0, 0, 0);
                }
                acc[ct] = a;
            }
        }

        const int tn = t + (int)gridDim.x;
        const int sn = tn * 8 + wave;
        // prefetch next strip BEFORE this strip's stores (vmcnt FIFO: loads
        // older than stores => consuming them tolerates outstanding stores)
        if (tn < NTB && sn < S) prefetch_x(x, sn, lm, q4, pf);

        if (active) {
            // ---- epilogue: q = 1/(1+dist2), in-wave row sums ----
            float xs4[4];
            #pragma unroll
            for (int r = 0; r < 4; ++r) xs4[r] = __shfl(xq, q4 * 4 + r);

            float rsum[4] = {0.f, 0.f, 0.f, 0.f};
            #pragma unroll
            for (int ct = 0; ct < 16; ++ct) {
                const float cq = csq_s[ct * 16 + lm];
                #pragma unroll
                for (int r = 0; r < 4; ++r) {
                    float d2 = fmaf(-2.f, acc[ct][r], xs4[r] + cq);
                    d2 = fmaxf(d2, 0.f);
                    float q = __builtin_amdgcn_rcpf(1.f + d2);
                    acc[ct][r] = q;
                    rsum[r] += q;
                }
            }
            #pragma unroll
            for (int r = 0; r < 4; ++r) {
                rsum[r] += __shfl_xor(rsum[r], 1);
                rsum[r] += __shfl_xor(rsum[r], 2);
                rsum[r] += __shfl_xor(rsum[r], 4);
                rsum[r] += __shfl_xor(rsum[r], 8);
                rsum[r] = __builtin_amdgcn_rcpf(rsum[r]);
            }

            // pin: prefetch issue stays above the store burst
            __builtin_amdgcn_sched_barrier(0);

            // ---- wave-private LDS transpose -> 16 contiguous NT x4 stores ----
            #pragma unroll
            for (int r = 0; r < 4; ++r) {
                float* lw = &lt[wave][r & 1][q4][0];
                const float inv = rsum[r];
                #pragma unroll
                for (int ct = 0; ct < 16; ++ct)
                    lw[ct * 16 + lm] = acc[ct][r] * inv;
                asm volatile("s_waitcnt lgkmcnt(0)" ::: "memory");
                #pragma unroll
                for (int j = 0; j < 4; ++j) {
                    const floatx4 v = *(const floatx4*)&lt[wave][r & 1][j][lane * 4];
                    __builtin_nontemporal_store(v,
                        (floatx4*)(out + ((size_t)s * 16 + j * 4 + r) * NK + lane * 4));
                }
            }
        }

        t = tn;
        s = sn;
    }
}

extern "C" void kernel_launch(void* const* d_in, const int* in_sizes, int n_in,
                              void* d_out, int out_size, void* d_ws, size_t ws_size,
                              hipStream_t stream) {
    const float* x = (const float*)d_in[0];   // [200000, 128] fp32
    const float* c = (const float*)d_in[1];   // [256, 128] fp32
    float* out = (float*)d_out;               // [200000, 256] fp32
    unsigned short* wb = (unsigned short*)d_ws;            // 64 KiB packed B
    float* wcsq = (float*)((char*)d_ws + 65536);           // 1 KiB csq
    const int N = in_sizes[0] / DIM;          // 200000
    const int S = N / 16;                     // 12500 strips
    const int NTB = (S + 7) / 8;              // 1563 block-iterations

    prep_clusters<<<dim3(9), dim3(512), 0, stream>>>(c, wb, wcsq);
    const int grid = NTB < 512 ? NTB : 512;
    cluster_q_v6<<<dim3(grid), dim3(512), 0, stream>>>(x, wb, wcsq, out, S, NTB);
}